// Round 4
// baseline (2033.801 us; speedup 1.0000x reference)
//
#include <hip/hip_runtime.h>
#include <math.h>

#define KTOP 8
#define MSLOT 16
#define TSTEPS 256
#define NBPB 2            // batches per block
#define NB 32             // 64 batches / 2
#define NTHREADS 640      // 10 waves: per batch 1 serial + 4 worker waves
#define NWORK 256
#define EPT 8
#define DIM_ 2048

static_assert(NWORK * EPT == DIM_, "mapping");

#define DPP0(src, ctrl, rm) __builtin_amdgcn_update_dpp(0, (src), (ctrl), (rm), 0xf, true)

// ---- f64 packed-key helpers: key = [f32bits(|c|)]:[((2047-e)<<5)|slot] ----
// positive, unique (e unique), never NaN/inf. bound_ctrl zero-fill = identity.
__device__ __forceinline__ void ced(double &a, double &b) {
  double mx = fmax(a, b);
  b = fmin(a, b);
  a = mx;
}

// Batcher odd-even mergesort, 8 elems, descending (19 CE)
__device__ __forceinline__ void sort8_desc(double k[8]) {
  ced(k[0],k[1]); ced(k[2],k[3]); ced(k[4],k[5]); ced(k[6],k[7]);
  ced(k[0],k[2]); ced(k[1],k[3]); ced(k[4],k[6]); ced(k[5],k[7]);
  ced(k[1],k[2]); ced(k[5],k[6]);
  ced(k[0],k[4]); ced(k[1],k[5]); ced(k[2],k[6]); ced(k[3],k[7]);
  ced(k[2],k[4]); ced(k[3],k[5]);
  ced(k[1],k[2]); ced(k[3],k[4]); ced(k[5],k[6]);
}

// merge-reduction level: pull partner's sorted-desc 8-list via DPP,
// half-clean (top-8 of union), bitonic resort.
template <int CTRL, int RM>
__device__ __forceinline__ void merge_level(double k[8]) {
  double b[8];
#pragma unroll
  for (int i = 0; i < 8; i++) {
    int lo = DPP0(__double2loint(k[i]), CTRL, RM);
    int hi = DPP0(__double2hiint(k[i]), CTRL, RM);
    b[i] = __hiloint2double(hi, lo);
  }
#pragma unroll
  for (int i = 0; i < 8; i++) k[i] = fmax(k[i], b[7 - i]);
  ced(k[0],k[4]); ced(k[1],k[5]); ced(k[2],k[6]); ced(k[3],k[7]);
  ced(k[0],k[2]); ced(k[1],k[3]); ced(k[4],k[6]); ced(k[5],k[7]);
  ced(k[0],k[1]); ced(k[2],k[3]); ced(k[4],k[5]); ced(k[6],k[7]);
}

#define FMAX_STAGE(x, ctrl, rm)                                                \
  x = fmaxf(x, __int_as_float(DPP0(__float_as_int(x), ctrl, rm)))
#define FADD_STAGE(x, ctrl, rm)                                                \
  x = x + __int_as_float(DPP0(__float_as_int(x), ctrl, rm))

__device__ __forceinline__ float wave_max_f32(float x) {
  FMAX_STAGE(x, 0x111, 0xf);
  FMAX_STAGE(x, 0x112, 0xf);
  FMAX_STAGE(x, 0x114, 0xf);
  FMAX_STAGE(x, 0x118, 0xf);
  FMAX_STAGE(x, 0x142, 0xa);
  FMAX_STAGE(x, 0x143, 0xc);
  return x; // lane 63
}
__device__ __forceinline__ float wave_sum_f32(float x) {
  FADD_STAGE(x, 0x111, 0xf);
  FADD_STAGE(x, 0x112, 0xf);
  FADD_STAGE(x, 0x114, 0xf);
  FADD_STAGE(x, 0x118, 0xf);
  FADD_STAGE(x, 0x142, 0xa);
  FADD_STAGE(x, 0x143, 0xc);
  return x; // lane 63
}
__device__ __forceinline__ int rl63(int v) {
  return __builtin_amdgcn_readlane(v, 63);
}

// barrier with LDS-only drain: global loads/stores stay in flight across it
__device__ __forceinline__ void barrier_lds() {
  asm volatile("s_waitcnt lgkmcnt(0)\n\ts_barrier" ::: "memory");
}

__global__ void __launch_bounds__(NTHREADS)
me_fused(const float *__restrict__ x, const float *__restrict__ tape_re,
         const float *__restrict__ tape_im, const float *__restrict__ eta_param,
         const float *__restrict__ tbias_re, const float *__restrict__ tbias_im,
         float *__restrict__ out) {
  __shared__ float2 dxy[NBPB][DIM_];                    // 32 KB scatter deltas
  __shared__ unsigned long long cand_key[NBPB][4 * KTOP];
  __shared__ float4 cand_val[NBPB][4 * KTOP];           // (cr,ci,vre,vim)
  __shared__ float red_sh[NBPB][4];

  const int tid = threadIdx.x;
  const int lane = tid & 63;
  const int wid = tid >> 6;
  const int q = (wid >= 5) ? 1 : 0;     // batch slot within block
  const int gw = wid - 5 * q;           // 0 = serial wave, 1..4 = workers
  const int wtid = (gw - 1) * 64 + lane;
  const int b = blockIdx.x * NBPB + q;

  const float eta = fabsf(eta_param[0]);

  // zero dxy once (wave0 re-zeroes only touched endpoints per step)
  for (int i = tid; i < NBPB * DIM_; i += NTHREADS)
    ((float2 *)dxy)[i] = make_float2(0.f, 0.f);

  float vre[EPT], vim[EPT], tbre_[EPT], tbim_[EPT];
  float hcur[EPT], hnext[EPT];
  int elo[EPT];
  const float *xb = x + (size_t)b * TSTEPS * DIM_;

  if (gw > 0) {
    float acc = 0.f;
#pragma unroll
    for (int j = 0; j < EPT; j++) {
      int e = wtid + NWORK * j;
      elo[j] = (2047 - e) << 5;
      float a = tape_re[e], c2 = tape_im[e];
      vre[j] = a; vim[j] = c2;
      tbre_[j] = tbias_re[e]; tbim_[j] = tbias_im[e];
      hcur[j] = xb[e]; hnext[j] = hcur[j];
      acc += a * a + c2 * c2;
    }
    float ws = wave_sum_f32(acc);
    if (lane == 63) red_sh[q][gw - 1] = ws;
  }

  // transient slots in serial-wave registers (lanes 0..15)
  int s_ti = 0, s_tj = 0, s_cnt = 0;
  float s_mre = 0.f, s_mim = 0.f;

  barrier_lds();

  for (int t = 0; t < TSTEPS; t++) {
    // ====== [A] workers: keys + wave top-8 + candidate key/value export ======
    if (gw > 0) {
      double key[EPT];
      float cr8[EPT], ci8[EPT];
#pragma unroll
      for (int j = 0; j < EPT; j++) {
        float h = hcur[j];
        float cr = h * vre[j], ci = h * vim[j];
        cr8[j] = cr; ci8[j] = ci;
        float av = sqrtf(cr * cr + ci * ci); // scale-invariant key
        key[j] = __hiloint2double(__float_as_int(av), elo[j]);
      }
      sort8_desc(key);
      merge_level<0x111, 0xf>(key);
      merge_level<0x112, 0xf>(key);
      merge_level<0x114, 0xf>(key);
      merge_level<0x118, 0xf>(key);
      merge_level<0x142, 0xa>(key);
      merge_level<0x143, 0xc>(key); // lane63 = wave sorted top-8
      int blo[KTOP];
#pragma unroll
      for (int r = 0; r < KTOP; r++)
        blo[r] = __builtin_amdgcn_readlane(__double2loint(key[r]), 63);
      if (lane == 63) {
#pragma unroll
        for (int r = 0; r < KTOP; r++) {
          int slot = (gw - 1) * KTOP + r;
          cand_key[q][slot] =
              (((unsigned long long)(unsigned)__double2hiint(key[r])) << 32) |
              (unsigned)(__double2loint(key[r]) | slot);
        }
      }
      // owners write candidate values
#pragma unroll
      for (int j = 0; j < EPT; j++) {
        int m = -1;
#pragma unroll
        for (int r = 0; r < KTOP; r++) m = (blo[r] == elo[j]) ? r : m;
        if (m >= 0)
          cand_val[q][(gw - 1) * KTOP + m] =
              make_float4(cr8[j], ci8[j], vre[j], vim[j]);
      }
    }
    barrier_lds(); // B1

    float ivn = 0.f;
    if (gw > 0) {
      float tot = red_sh[q][0] + red_sh[q][1] + red_sh[q][2] + red_sh[q][3];
      ivn = 1.f / fmaxf(sqrtf(tot), 1e-8f);
    }

    float osr[EPT], osi[EPT];

    if (gw == 0) {
      // ---- zero previous step's scatter endpoints (pre-scan values) ----
      if (lane < MSLOT) {
        dxy[q][s_ti] = make_float2(0.f, 0.f);
        dxy[q][s_tj] = make_float2(0.f, 0.f);
      }
      // ---- merge 4 sorted lists (lanes 0-3) ----
      double c[KTOP];
#pragma unroll
      for (int r = 0; r < KTOP; r++) {
        unsigned long long v = (lane < 4) ? cand_key[q][lane * KTOP + r] : 0ull;
        c[r] = __longlong_as_double((long long)v);
      }
      merge_level<0x111, 0xf>(c);
      merge_level<0x112, 0xf>(c); // lane 3 = global sorted top-8
      int gidx[KTOP], slt[KTOP];
#pragma unroll
      for (int r = 0; r < KTOP; r++) {
        int lo = __builtin_amdgcn_readlane(__double2loint(c[r]), 3);
        gidx[r] = 2047 - ((lo >> 5) & 0x7ff);
        slt[r] = lo & 31;
      }
      // ---- pair (ii,jj), row-major triu ----
      int pi = (lane < 28) ? lane : 27;
      int ii = 0, base = 0;
      if (pi >= 7)  { ii = 1; base = 7;  }
      if (pi >= 13) { ii = 2; base = 13; }
      if (pi >= 18) { ii = 3; base = 18; }
      if (pi >= 22) { ii = 4; base = 22; }
      if (pi >= 25) { ii = 5; base = 25; }
      if (pi >= 27) { ii = 6; base = 27; }
      int jj = ii + 1 + (pi - base);
      int gi = gidx[0], sli = slt[0];
      if (ii == 1) { gi = gidx[1]; sli = slt[1]; }
      if (ii == 2) { gi = gidx[2]; sli = slt[2]; }
      if (ii == 3) { gi = gidx[3]; sli = slt[3]; }
      if (ii == 4) { gi = gidx[4]; sli = slt[4]; }
      if (ii == 5) { gi = gidx[5]; sli = slt[5]; }
      if (ii == 6) { gi = gidx[6]; sli = slt[6]; }
      int gj = gidx[1], slj = slt[1];
      if (jj == 2) { gj = gidx[2]; slj = slt[2]; }
      if (jj == 3) { gj = gidx[3]; slj = slt[3]; }
      if (jj == 4) { gj = gidx[4]; slj = slt[4]; }
      if (jj == 5) { gj = gidx[5]; slj = slt[5]; }
      if (jj == 6) { gj = gidx[6]; slj = slt[6]; }
      if (jj == 7) { gj = gidx[7]; slj = slt[7]; }

      float4 c4i = cand_val[q][sli], c4j = cand_val[q][slj];
      // raw (unnormalized) score & mnew — scale-invariant decisions
      float score = c4i.x * c4j.x + c4i.y * c4j.y;
      bool valid = (lane < 28);
      bool pos = valid && (score > 0.f);
      unsigned long long posmask = __ballot(pos);
      int npos = __popcll(posmask);
      float pr = c4i.z * c4j.z - c4i.w * c4j.w;
      float pq2 = c4i.z * c4j.w + c4i.w * c4j.z;
      float ap = fmaxf(sqrtf(pr * pr + pq2 * pq2), 1e-8f);
      float mr = (0.05f * pr) / ap, mi = (0.05f * pq2) / ap;

      unsigned long long bmask = 0ull;
      if (npos > 0) {
        int nbind = (int)((float)npos * 0.15f);
        if (nbind < 1) nbind = 1;
        float val = pos ? score : -__builtin_inff();
        float th = 0.f;
        for (int k2 = 0; k2 < nbind; ++k2) {
          float mx = wave_max_f32(val);
          th = __int_as_float(rl63(__float_as_int(mx)));
          if (k2 + 1 < nbind) {
            unsigned long long em = __ballot(val == th);
            if (lane == (int)__builtin_ctzll(em)) val = -__builtin_inff();
          }
        }
        bool bind = valid && (score >= th);
        bmask = __ballot(bind);
      }
      // slot scan in pair order
      while (bmask) {
        int pp = (int)__builtin_ctzll(bmask);
        bmask &= bmask - 1;
        int pci = __builtin_amdgcn_readlane(gi, pp);
        int pcj = __builtin_amdgcn_readlane(gj, pp);
        int pmr = __builtin_amdgcn_readlane(__float_as_int(mr), pp);
        int pmi = __builtin_amdgcn_readlane(__float_as_int(mi), pp);
        bool isslot = (lane < MSLOT);
        bool match = isslot && (s_cnt > 0) &&
                     ((s_ti == pci && s_tj == pcj) ||
                      (s_ti == pcj && s_tj == pci));
        unsigned long long mm = __ballot(match);
        if (mm != 0ull) {
          if (lane == (int)__builtin_ctzll(mm)) s_cnt = 5; // refresh only
        } else {
          unsigned long long fm = __ballot(isslot && s_cnt <= 0);
          if (fm != 0ull && lane == (int)__builtin_ctzll(fm)) {
            s_ti = pci; s_tj = pcj;
            s_mre = __int_as_float(pmr); s_mim = __int_as_float(pmi);
            s_cnt = 5;
          }
        }
      }
      // decay + alive + scatter (dead slots add exact 0.0, like the ref)
      if (lane < MSLOT) {
        s_mre *= 0.9f; s_mim *= 0.9f; s_cnt -= 1;
        bool alive = (s_cnt > 0) &&
                     (sqrtf(s_mre * s_mre + s_mim * s_mim) > 1e-6f);
        if (!alive) { s_cnt = 0; s_mre = 0.f; s_mim = 0.f; }
        atomicAdd(&dxy[q][s_ti].x, 0.1f * s_mre);
        atomicAdd(&dxy[q][s_tj].x, 0.1f * s_mre);
        atomicAdd(&dxy[q][s_ti].y, 0.1f * s_mim);
        atomicAdd(&dxy[q][s_tj].y, 0.1f * s_mim);
      }
    } else {
      // ====== workers overlap the serial section ======
      if (t + 1 < TSTEPS) {
        const float *xr = xb + (size_t)(t + 1) * DIM_;
#pragma unroll
        for (int j = 0; j < EPT; j++) hnext[j] = xr[wtid + NWORK * j];
      }
      if (t > 0) {
        float *op = out + ((size_t)b * TSTEPS + (t - 1)) * DIM_;
#pragma unroll
        for (int j = 0; j < EPT; j++) {
          float sr = vre[j] * ivn, si = vim[j] * ivn;
          op[wtid + NWORK * j] = sqrtf(sr * sr + si * si);
        }
      }
      // speculative update (delta = 0; exact for untouched elements)
#pragma unroll
      for (int j = 0; j < EPT; j++) {
        float sri = vre[j] * ivn, sii2 = vim[j] * ivn;
        osr[j] = sri; osi[j] = sii2;
        float h = hcur[j];
        float car = h * sri, cai = h * sii2;
        bool res = (car > 1e-6f) && (fabsf(cai) < car);
        bool tor = (car < -1e-6f) || (fabsf(cai) >= fabsf(car));
        float m1 = (res || tor) ? 1.f : 0.f;
        float mt = tor ? 1.f : 0.f;
        float ur = eta * (car * m1 + mt * tbre_[j]);
        float ui = eta * (cai * m1 + mt * tbim_[j]);
        vre[j] = sri + ur; vim[j] = sii2 + ui;
      }
    }
    barrier_lds(); // B2

    // ====== [C] workers: sparse patch + norm ======
    if (gw > 0) {
      float2 dd[EPT];
#pragma unroll
      for (int j = 0; j < EPT; j++) dd[j] = dxy[q][wtid + NWORK * j];
      float acc2 = 0.f;
#pragma unroll
      for (int j = 0; j < EPT; j++) {
        if (dd[j].x != 0.f || dd[j].y != 0.f) {
          float ar = osr[j] + dd[j].x, ai = osi[j] + dd[j].y;
          float h = hcur[j];
          float car = h * ar, cai = h * ai;
          bool res = (car > 1e-6f) && (fabsf(cai) < car);
          bool tor = (car < -1e-6f) || (fabsf(cai) >= fabsf(car));
          float m1 = (res || tor) ? 1.f : 0.f;
          float mt = tor ? 1.f : 0.f;
          float ur = eta * (car * m1 + mt * tbre_[j]);
          float ui = eta * (cai * m1 + mt * tbim_[j]);
          vre[j] = osr[j] + ur; vim[j] = osi[j] + ui;
        }
        acc2 += vre[j] * vre[j] + vim[j] * vim[j];
      }
      float ws = wave_sum_f32(acc2);
      if (lane == 63) red_sh[q][gw - 1] = ws;
#pragma unroll
      for (int j = 0; j < EPT; j++) hcur[j] = hnext[j];
    }
  }

  // epilogue: final output row
  barrier_lds();
  if (gw > 0) {
    float tot = red_sh[q][0] + red_sh[q][1] + red_sh[q][2] + red_sh[q][3];
    float ivnF = 1.f / fmaxf(sqrtf(tot), 1e-8f);
    float *op = out + ((size_t)b * TSTEPS + (TSTEPS - 1)) * DIM_;
#pragma unroll
    for (int j = 0; j < EPT; j++) {
      float sr = vre[j] * ivnF, si = vim[j] * ivnF;
      op[wtid + NWORK * j] = sqrtf(sr * sr + si * si);
    }
  }
}

extern "C" void kernel_launch(void *const *d_in, const int *in_sizes, int n_in,
                              void *d_out, int out_size, void *d_ws,
                              size_t ws_size, hipStream_t stream) {
  const float *x = (const float *)d_in[0];
  const float *tre = (const float *)d_in[1];
  const float *tim = (const float *)d_in[2];
  const float *eta = (const float *)d_in[3];
  const float *tbre = (const float *)d_in[4];
  const float *tbim = (const float *)d_in[5];
  float *out = (float *)d_out;
  me_fused<<<NB, NTHREADS, 0, stream>>>(x, tre, tim, eta, tbre, tbim, out);
}